// Round 1
// baseline (424.708 us; speedup 1.0000x reference)
//
#include <hip/hip_runtime.h>
#include <cstdint>
#include <cstddef>

#define B_ 512
#define W_ 1024
#define L_ 64
#define J_ 8
#define I_ 32
#define O_ 128

// ws layout (floats):
// attn   : [B][J][W]   = 4194304
// best   : [J][B][L]   = 262144
// conf   : [B]         = 512
// partial: [64][B][I]  = 1048576   (64 slices = (j,lgroup))

// ---------------------------------------------------------------- K1: scores + softmax + attn + conf
__global__ __launch_bounds__(256) void k1_scores(const float* __restrict__ wm,
    const float* __restrict__ constants, const float* __restrict__ gammas,
    float* __restrict__ attn, float* __restrict__ conf)
{
  __shared__ __align__(16) float wc[J_][L_];   // (1-g)*c
  __shared__ __align__(16) float w1s[J_][L_];  // (1-g)
  __shared__ float Aj[J_];
  __shared__ __align__(16) float sc[J_][W_];   // scores, then e
  __shared__ float redA[4][J_];
  __shared__ float redB[4][J_];
  __shared__ float sminS[J_];
  __shared__ float denS[J_];

  const int tid = threadIdx.x;
  const int b = blockIdx.x;

  for (int idx = tid; idx < J_*L_; idx += 256) {
    int j = idx >> 6, l = idx & 63;
    float g = gammas[idx];
    g = fminf(fmaxf(g, 0.f), 1.f);
    float c = constants[idx];
    float w1 = 1.f - g;
    w1s[j][l] = w1;
    wc[j][l]  = w1 * c;
  }
  __syncthreads();
  if (tid < J_) {
    float a = 0.f;
    for (int l = 0; l < L_; ++l) a += wc[tid][l] * constants[tid*L_ + l];
    Aj[tid] = a;
  }
  __syncthreads();

  const float* wmb = wm + (size_t)b * (W_*L_);
  float acc1[J_][4], acc2[J_][4];
  #pragma unroll
  for (int j = 0; j < J_; ++j)
    #pragma unroll
    for (int wi = 0; wi < 4; ++wi) { acc1[j][wi] = 0.f; acc2[j][wi] = 0.f; }

  #pragma unroll
  for (int c = 0; c < 16; ++c) {
    float4 x[4], xs[4];
    #pragma unroll
    for (int wi = 0; wi < 4; ++wi) {
      x[wi] = *(const float4*)(wmb + (size_t)(tid + wi*256)*L_ + c*4);
      xs[wi].x = x[wi].x * x[wi].x;
      xs[wi].y = x[wi].y * x[wi].y;
      xs[wi].z = x[wi].z * x[wi].z;
      xs[wi].w = x[wi].w * x[wi].w;
    }
    #pragma unroll
    for (int j = 0; j < J_; ++j) {
      float4 a4 = *(const float4*)&wc[j][c*4];
      float4 b4 = *(const float4*)&w1s[j][c*4];
      #pragma unroll
      for (int wi = 0; wi < 4; ++wi) {
        acc1[j][wi] = fmaf(a4.x, x[wi].x, acc1[j][wi]);
        acc1[j][wi] = fmaf(a4.y, x[wi].y, acc1[j][wi]);
        acc1[j][wi] = fmaf(a4.z, x[wi].z, acc1[j][wi]);
        acc1[j][wi] = fmaf(a4.w, x[wi].w, acc1[j][wi]);
        acc2[j][wi] = fmaf(b4.x, xs[wi].x, acc2[j][wi]);
        acc2[j][wi] = fmaf(b4.y, xs[wi].y, acc2[j][wi]);
        acc2[j][wi] = fmaf(b4.z, xs[wi].z, acc2[j][wi]);
        acc2[j][wi] = fmaf(b4.w, xs[wi].w, acc2[j][wi]);
      }
    }
  }

  // scores into LDS + per-thread min
  float lmin[J_];
  #pragma unroll
  for (int j = 0; j < J_; ++j) lmin[j] = 3.4e38f;
  #pragma unroll
  for (int j = 0; j < J_; ++j) {
    float aj = Aj[j];
    #pragma unroll
    for (int wi = 0; wi < 4; ++wi) {
      float s = aj - 2.f*acc1[j][wi] + acc2[j][wi];
      sc[j][tid + wi*256] = s;
      lmin[j] = fminf(lmin[j], s);
    }
  }
  // wave-level min, then block
  #pragma unroll
  for (int j = 0; j < J_; ++j)
    #pragma unroll
    for (int off = 32; off; off >>= 1)
      lmin[j] = fminf(lmin[j], __shfl_xor(lmin[j], off));
  const int wv = tid >> 6;
  if ((tid & 63) == 0) {
    #pragma unroll
    for (int j = 0; j < J_; ++j) redA[wv][j] = lmin[j];
  }
  __syncthreads();
  if (tid < J_) {
    sminS[tid] = fminf(fminf(redA[0][tid], redA[1][tid]),
                       fminf(redA[2][tid], redA[3][tid]));
  }
  __syncthreads();

  // e = exp(smin - s); sums of e and e*s
  float esum[J_], msum[J_];
  #pragma unroll
  for (int j = 0; j < J_; ++j) { esum[j] = 0.f; msum[j] = 0.f; }
  #pragma unroll
  for (int j = 0; j < J_; ++j) {
    float m = sminS[j];
    #pragma unroll
    for (int wi = 0; wi < 4; ++wi) {
      int w = tid + wi*256;
      float s = sc[j][w];
      float e = __expf(m - s);
      esum[j] += e;
      msum[j] += e * s;
      sc[j][w] = e;
    }
  }
  #pragma unroll
  for (int j = 0; j < J_; ++j)
    #pragma unroll
    for (int off = 32; off; off >>= 1) {
      esum[j] += __shfl_xor(esum[j], off);
      msum[j] += __shfl_xor(msum[j], off);
    }
  if ((tid & 63) == 0) {
    #pragma unroll
    for (int j = 0; j < J_; ++j) { redA[wv][j] = esum[j]; redB[wv][j] = msum[j]; }
  }
  __syncthreads();
  if (tid < J_) {
    float d  = redA[0][tid] + redA[1][tid] + redA[2][tid] + redA[3][tid];
    float mn = redB[0][tid] + redB[1][tid] + redB[2][tid] + redB[3][tid];
    denS[tid] = d;
    redB[0][tid] = mn / d;   // per-j expected score
  }
  __syncthreads();
  if (tid == 0) {
    float mq = 0.f;
    #pragma unroll
    for (int j = 0; j < J_; ++j) mq += redB[0][j];
    conf[b] = __expf(-mq);
  }
  // write normalized attn
  float* ab = attn + (size_t)b * (J_*W_);
  #pragma unroll
  for (int j = 0; j < J_; ++j) {
    float rd = 1.f / denS[j];
    float4 e4 = *(const float4*)&sc[j][tid*4];
    float4 o4;
    o4.x = e4.x * rd; o4.y = e4.y * rd; o4.z = e4.z * rd; o4.w = e4.w * rd;
    *(float4*)(ab + j*W_ + tid*4) = o4;
  }
}

// ---------------------------------------------------------------- K2: best = attn @ wm
__global__ __launch_bounds__(512) void k2_best(const float* __restrict__ wm,
    const float* __restrict__ attn, float* __restrict__ best)
{
  const int b = blockIdx.x, tid = threadIdx.x;
  const int j = tid >> 6, lane = tid & 63;
  const int wsub = lane >> 4, l4 = (lane & 15) * 4;
  const float* wmb = wm + (size_t)b * (W_*L_);
  const float* ap  = attn + (size_t)b * (J_*W_) + j*W_;
  float4 acc = make_float4(0.f, 0.f, 0.f, 0.f);
  #pragma unroll 8
  for (int wb = 0; wb < W_; wb += 4) {
    int w = wb + wsub;
    float a = ap[w];
    float4 x = *(const float4*)(wmb + (size_t)w*L_ + l4);
    acc.x = fmaf(a, x.x, acc.x);
    acc.y = fmaf(a, x.y, acc.y);
    acc.z = fmaf(a, x.z, acc.z);
    acc.w = fmaf(a, x.w, acc.w);
  }
  #pragma unroll
  for (int off = 16; off <= 32; off <<= 1) {
    acc.x += __shfl_xor(acc.x, off);
    acc.y += __shfl_xor(acc.y, off);
    acc.z += __shfl_xor(acc.z, off);
    acc.w += __shfl_xor(acc.w, off);
  }
  if (lane < 16)
    *(float4*)(best + ((size_t)j*B_ + b)*L_ + l4) = acc;
}

// ---------------------------------------------------------------- K3: slot logits + softmax-over-i + scaled contribution
__global__ __launch_bounds__(256) void k3_slot(const float* __restrict__ slot_w,
    const float* __restrict__ slot_b, const float* __restrict__ best,
    float* __restrict__ partial)
{
  const int bx = blockIdx.x;            // 0..63 : j*8 + lgroup
  const int j = bx >> 3, lg = bx & 7;
  const int bc = blockIdx.y;            // 0..15 : b-chunk of 32
  const int tid = threadIdx.x;
  const int wv = tid >> 6, lane = tid & 63;
  const int l2 = lane >> 5, i = lane & 31;
  const int l = lg*8 + wv*2 + l2;
  const int r = l*I_ + i;

  const float* swr = slot_w + ((size_t)j*(L_*I_) + r) * L_;
  float sw[L_];
  #pragma unroll
  for (int c = 0; c < 16; ++c) {
    float4 t = ((const float4*)swr)[c];
    sw[c*4+0] = t.x; sw[c*4+1] = t.y; sw[c*4+2] = t.z; sw[c*4+3] = t.w;
  }
  const float sb = slot_b[j*(L_*I_) + r];
  const float* bestj = best + (size_t)j * B_ * L_;
  float* pout = partial + (size_t)bx * (B_*I_);
  const int lidx = lg*8 + wv*2;

  for (int bi = 0; bi < 32; ++bi) {
    const int b = bc*32 + bi;
    const float* bw = bestj + (size_t)b * L_;   // wave-uniform -> scalar loads
    float logit = sb;
    #pragma unroll
    for (int c = 0; c < L_; ++c) logit = fmaf(bw[c], sw[c], logit);
    float m = logit;
    #pragma unroll
    for (int mask = 16; mask; mask >>= 1) m = fmaxf(m, __shfl_xor(m, mask));
    float e = __expf(logit - m);
    float s = e;
    #pragma unroll
    for (int mask = 16; mask; mask >>= 1) s += __shfl_xor(s, mask);
    float b0v = bw[lidx], b1v = bw[lidx + 1];
    float bv = l2 ? b1v : b0v;
    float contrib = (e / s) * bv;
    contrib += __shfl_xor(contrib, 32);   // sum over the 2 l's in this wave
    if (l2 == 0) pout[(size_t)b*I_ + i] = contrib;
  }
}

// ---------------------------------------------------------------- K4: reduce partials + body + head + confidence
__global__ __launch_bounds__(128) void k4_head(const float* __restrict__ partial,
    const float* __restrict__ best, const float* __restrict__ gammas,
    const float* __restrict__ body_w, const float* __restrict__ body_b,
    const float* __restrict__ head_w, const float* __restrict__ head_b,
    const float* __restrict__ conf, float* __restrict__ out)
{
  __shared__ float gavg[J_];
  __shared__ float cvred[4][I_];
  __shared__ float cvf[I_];
  const int b = blockIdx.x, tid = threadIdx.x;
  if (tid < J_) {
    float gsum = 0.f;
    for (int l = 0; l < L_; ++l) {
      float g = gammas[tid*L_ + l];
      gsum += fminf(fmaxf(g, 0.f), 1.f);
    }
    gavg[tid] = gsum * (1.f / L_);
  }
  const int i = tid & 31, q = tid >> 5;
  float acc = 0.f;
  for (int s = q; s < 64; s += 4)
    acc += partial[((size_t)s*B_ + b)*I_ + i];
  cvred[q][i] = acc;
  __syncthreads();
  if (tid < I_) {
    float cv = cvred[0][i] + cvred[1][i] + cvred[2][i] + cvred[3][i];
    #pragma unroll
    for (int j = 0; j < J_; ++j) {
      const float* bw   = best + ((size_t)j*B_ + b)*L_;
      const float* wrow = body_w + (size_t)(j*I_ + i)*L_;
      float d = body_b[j*I_ + i];
      for (int c = 0; c < L_; ++c) d = fmaf(bw[c], wrow[c], d);
      cv += gavg[j] * d;
    }
    cvf[i] = cv;
  }
  __syncthreads();
  float oacc = head_b[tid];
  #pragma unroll
  for (int i2 = 0; i2 < I_; ++i2) oacc = fmaf(cvf[i2], head_w[tid*I_ + i2], oacc);
  out[(size_t)b*O_ + tid] = conf[b] * oacc;
}

extern "C" void kernel_launch(void* const* d_in, const int* in_sizes, int n_in,
                              void* d_out, int out_size, void* d_ws, size_t ws_size,
                              hipStream_t stream) {
  const float* wm        = (const float*)d_in[0];
  const float* constants = (const float*)d_in[1];
  const float* gammas    = (const float*)d_in[2];
  const float* body_w    = (const float*)d_in[3];
  const float* body_b    = (const float*)d_in[4];
  const float* slot_w    = (const float*)d_in[5];
  const float* slot_b    = (const float*)d_in[6];
  const float* head_w    = (const float*)d_in[7];
  const float* head_b    = (const float*)d_in[8];
  float* out = (float*)d_out;

  float* ws      = (float*)d_ws;
  float* attn    = ws;                                  // 4194304
  float* best    = attn + (size_t)B_*J_*W_;             // 262144
  float* conf    = best + (size_t)J_*B_*L_;             // 512
  float* partial = conf + B_;                           // 1048576

  hipLaunchKernelGGL(k1_scores, dim3(B_), dim3(256), 0, stream,
                     wm, constants, gammas, attn, conf);
  hipLaunchKernelGGL(k2_best, dim3(B_), dim3(512), 0, stream,
                     wm, attn, best);
  hipLaunchKernelGGL(k3_slot, dim3(64, 16), dim3(256), 0, stream,
                     slot_w, slot_b, best, partial);
  hipLaunchKernelGGL(k4_head, dim3(B_), dim3(128), 0, stream,
                     partial, best, gammas, body_w, body_b, head_w, head_b, conf, out);
}

// Round 2
// 351.008 us; speedup vs baseline: 1.2100x; 1.2100x over previous
//
#include <hip/hip_runtime.h>
#include <cstdint>
#include <cstddef>

#define B_ 512
#define W_ 1024
#define L_ 64
#define J_ 8
#define I_ 32
#define O_ 128

// ws layout (floats):
// wcg  : [J][L]      = 512    @ 0
// w1g  : [J][L]      = 512    @ 512
// Ag   : [J] (+pad)  = 16     @ 1024
// best : [J][B][L]   = 262144 @ 1040
// conf : [B]         = 512    @ 1040+262144
// partial:[64][B][I] = 1048576

// ---------------------------------------------------------------- K0: tiny precompute of wc, w1, A
__global__ __launch_bounds__(64) void k0_prep(const float* __restrict__ constants,
    const float* __restrict__ gammas, float* __restrict__ wcg,
    float* __restrict__ w1g, float* __restrict__ Ag)
{
  const int l = threadIdx.x;  // 64 threads
  #pragma unroll
  for (int j = 0; j < J_; ++j) {
    float g = gammas[j*L_ + l];
    g = fminf(fmaxf(g, 0.f), 1.f);
    float c = constants[j*L_ + l];
    float w1 = 1.f - g;
    w1g[j*L_ + l] = w1;
    wcg[j*L_ + l] = w1 * c;
  }
  if (l < J_) {
    float a = 0.f;
    for (int c = 0; c < L_; ++c) {
      float g = gammas[l*L_ + c];
      g = fminf(fmaxf(g, 0.f), 1.f);
      float cc = constants[l*L_ + c];
      a += (1.f - g) * cc * cc;
    }
    Ag[l] = a;
  }
}

// ---------------------------------------------------------------- K12: fused scores + softmax + best + conf (single wm pass)
__global__ __launch_bounds__(256, 2) void k12_fused(const float* __restrict__ wm,
    const float* __restrict__ wcg, const float* __restrict__ w1g,
    const float* __restrict__ Ag, float* __restrict__ best, float* __restrict__ conf)
{
  __shared__ __align__(16) float xs[256 * 68];   // wm chunk, padded rows (69632 B)
  __shared__ __align__(16) float es[J_ * 256];   // e values, transposed (8192 B)
  __shared__ float redA[4][J_], redB[4][J_];
  __shared__ float bcast[J_];

  const int tid = threadIdx.x, b = blockIdx.x;
  const int lane = tid & 63, wv = tid >> 6;
  const int lq = tid & 15, wsl = tid >> 4;

  float accb[J_][4];
  #pragma unroll
  for (int j = 0; j < J_; ++j)
    #pragma unroll
    for (int q = 0; q < 4; ++q) accb[j][q] = 0.f;
  float esum[J_], msum[J_], m0[J_];
  #pragma unroll
  for (int j = 0; j < J_; ++j) { esum[j] = 0.f; msum[j] = 0.f; }

  const float* wmb = wm + (size_t)b * (W_*L_);

  for (int ch = 0; ch < 4; ++ch) {
    __syncthreads();   // xs about to be overwritten (prev accum read it)
    // ---- stage 256 rows, fully coalesced
    const float4* src = (const float4*)(wmb + ch * (256*L_));
    #pragma unroll
    for (int k = 0; k < 16; ++k) {
      int f = k*256 + tid;
      float4 v = src[f];
      int w = f >> 4, lw = f & 15;
      *(float4*)&xs[w*68 + lw*4] = v;
    }
    __syncthreads();

    // ---- score: thread owns w = tid
    float a1[J_], a2[J_];
    #pragma unroll
    for (int j = 0; j < J_; ++j) { a1[j] = 0.f; a2[j] = 0.f; }
    #pragma unroll
    for (int c = 0; c < 16; ++c) {
      float4 x = *(const float4*)&xs[tid*68 + c*4];
      float4 xq;
      xq.x = x.x*x.x; xq.y = x.y*x.y; xq.z = x.z*x.z; xq.w = x.w*x.w;
      #pragma unroll
      for (int j = 0; j < J_; ++j) {
        float4 wc4 = *(const float4*)(wcg + j*L_ + c*4);   // uniform -> s_load
        float4 w14 = *(const float4*)(w1g + j*L_ + c*4);   // uniform -> s_load
        a1[j] = fmaf(wc4.x, x.x, a1[j]);
        a1[j] = fmaf(wc4.y, x.y, a1[j]);
        a1[j] = fmaf(wc4.z, x.z, a1[j]);
        a1[j] = fmaf(wc4.w, x.w, a1[j]);
        a2[j] = fmaf(w14.x, xq.x, a2[j]);
        a2[j] = fmaf(w14.y, xq.y, a2[j]);
        a2[j] = fmaf(w14.z, xq.z, a2[j]);
        a2[j] = fmaf(w14.w, xq.w, a2[j]);
      }
    }
    float s[J_];
    #pragma unroll
    for (int j = 0; j < J_; ++j) s[j] = Ag[j] - 2.f*a1[j] + a2[j];

    // ---- stabilizer from chunk 0 (scores >= 0, so exp(m0 - s) <= exp(m0): safe)
    if (ch == 0) {
      #pragma unroll
      for (int j = 0; j < J_; ++j) {
        float mn = s[j];
        #pragma unroll
        for (int off = 1; off < 64; off <<= 1)
          mn = fminf(mn, __shfl_xor(mn, off));
        if (lane == 0) redA[wv][j] = mn;
      }
      __syncthreads();
      if (tid < J_)
        bcast[tid] = fminf(fminf(redA[0][tid], redA[1][tid]),
                           fminf(redA[2][tid], redA[3][tid]));
      __syncthreads();
      #pragma unroll
      for (int j = 0; j < J_; ++j) m0[j] = bcast[j];
    }

    // ---- e + running sums + write e to LDS (transposed)
    #pragma unroll
    for (int j = 0; j < J_; ++j) {
      float e = __expf(m0[j] - s[j]);
      esum[j] += e;
      msum[j] = fmaf(e, s[j], msum[j]);
      es[j*256 + tid] = e;
    }
    __syncthreads();

    // ---- accumulate best: thread owns (lq, w in [wsl*16, wsl*16+16))
    #pragma unroll
    for (int tg = 0; tg < 4; ++tg) {
      float4 e4[J_];
      #pragma unroll
      for (int j = 0; j < J_; ++j)
        e4[j] = *(const float4*)&es[j*256 + wsl*16 + tg*4];
      #pragma unroll
      for (int t = 0; t < 4; ++t) {
        int w = wsl*16 + tg*4 + t;
        float4 x = *(const float4*)&xs[w*68 + lq*4];
        #pragma unroll
        for (int j = 0; j < J_; ++j) {
          float ej = (t == 0) ? e4[j].x : (t == 1) ? e4[j].y
                   : (t == 2) ? e4[j].z : e4[j].w;
          accb[j][0] = fmaf(ej, x.x, accb[j][0]);
          accb[j][1] = fmaf(ej, x.y, accb[j][1]);
          accb[j][2] = fmaf(ej, x.z, accb[j][2]);
          accb[j][3] = fmaf(ej, x.w, accb[j][3]);
        }
      }
    }
  }

  // ---- reduce esum/msum over the block
  #pragma unroll
  for (int j = 0; j < J_; ++j) {
    float e = esum[j], m = msum[j];
    #pragma unroll
    for (int off = 1; off < 64; off <<= 1) {
      e += __shfl_xor(e, off);
      m += __shfl_xor(m, off);
    }
    if (lane == 0) { redA[wv][j] = e; redB[wv][j] = m; }
  }
  __syncthreads();
  if (tid < J_) {
    float E = redA[0][tid] + redA[1][tid] + redA[2][tid] + redA[3][tid];
    float M = redB[0][tid] + redB[1][tid] + redB[2][tid] + redB[3][tid];
    bcast[tid]   = 1.f / E;   // inv denom
    redB[0][tid] = M / E;     // expected score per j
  }
  __syncthreads();
  if (tid == 0) {
    float mq = 0.f;
    #pragma unroll
    for (int j = 0; j < J_; ++j) mq += redB[0][j];
    conf[b] = __expf(-mq);
  }

  // ---- reduce best partials across the 16 w-slots (reuse xs)
  #pragma unroll
  for (int j = 0; j < J_; ++j)
    *(float4*)&xs[((wsl*J_ + j)*16 + lq)*4] = *(float4*)accb[j];
  __syncthreads();
  if (tid < J_*16) {
    int j = tid >> 4, q = tid & 15;
    float4 sum = make_float4(0.f, 0.f, 0.f, 0.f);
    #pragma unroll
    for (int w2 = 0; w2 < 16; ++w2) {
      float4 p = *(const float4*)&xs[((w2*J_ + j)*16 + q)*4];
      sum.x += p.x; sum.y += p.y; sum.z += p.z; sum.w += p.w;
    }
    float iv = bcast[j];
    sum.x *= iv; sum.y *= iv; sum.z *= iv; sum.w *= iv;
    *(float4*)&best[((size_t)j*B_ + b)*L_ + q*4] = sum;
  }
}

// ---------------------------------------------------------------- K3: slot logits + softmax-over-i + scaled contribution
__global__ __launch_bounds__(256) void k3_slot(const float* __restrict__ slot_w,
    const float* __restrict__ slot_b, const float* __restrict__ best,
    float* __restrict__ partial)
{
  const int bx = blockIdx.y;            // 0..63 : j*8 + lgroup  (slow dim)
  const int j = bx >> 3, lg = bx & 7;
  const int bc = blockIdx.x;            // 0..15 : b-chunk of 32 (fast dim -> L2 reuse)
  const int tid = threadIdx.x;
  const int wv = tid >> 6, lane = tid & 63;
  const int l2 = lane >> 5, i = lane & 31;
  const int l = lg*8 + wv*2 + l2;
  const int r = l*I_ + i;

  const float* swr = slot_w + ((size_t)j*(L_*I_) + r) * L_;
  float sw[L_];
  #pragma unroll
  for (int c = 0; c < 16; ++c) {
    float4 t = ((const float4*)swr)[c];
    sw[c*4+0] = t.x; sw[c*4+1] = t.y; sw[c*4+2] = t.z; sw[c*4+3] = t.w;
  }
  const float sb = slot_b[j*(L_*I_) + r];
  const float* bestj = best + (size_t)j * B_ * L_;
  float* pout = partial + (size_t)(bx) * (B_*I_);
  const int lidx = lg*8 + wv*2;

  for (int bi = 0; bi < 32; ++bi) {
    const int b = bc*32 + bi;
    const float* bw = bestj + (size_t)b * L_;   // block-uniform -> s_load
    float p0 = sb, p1 = 0.f, p2 = 0.f, p3 = 0.f;
    #pragma unroll
    for (int c = 0; c < L_; c += 4) {
      p0 = fmaf(bw[c+0], sw[c+0], p0);
      p1 = fmaf(bw[c+1], sw[c+1], p1);
      p2 = fmaf(bw[c+2], sw[c+2], p2);
      p3 = fmaf(bw[c+3], sw[c+3], p3);
    }
    float logit = (p0 + p1) + (p2 + p3);
    float m = logit;
    #pragma unroll
    for (int mask = 16; mask; mask >>= 1) m = fmaxf(m, __shfl_xor(m, mask));
    float e = __expf(logit - m);
    float ssum = e;
    #pragma unroll
    for (int mask = 16; mask; mask >>= 1) ssum += __shfl_xor(ssum, mask);
    float b0v = bw[lidx], b1v = bw[lidx + 1];
    float bv = l2 ? b1v : b0v;
    float contrib = (e / ssum) * bv;
    contrib += __shfl_xor(contrib, 32);   // sum over the 2 l's in this wave
    if (l2 == 0) pout[(size_t)b*I_ + i] = contrib;
  }
}

// ---------------------------------------------------------------- K4: reduce partials + body + head + confidence
__global__ __launch_bounds__(128) void k4_head(const float* __restrict__ partial,
    const float* __restrict__ best, const float* __restrict__ gammas,
    const float* __restrict__ body_w, const float* __restrict__ body_b,
    const float* __restrict__ head_w, const float* __restrict__ head_b,
    const float* __restrict__ conf, float* __restrict__ out)
{
  __shared__ float gavg[J_];
  __shared__ float cvred[4][I_];
  __shared__ float cvf[I_];
  const int b = blockIdx.x, tid = threadIdx.x;
  if (tid < J_) {
    float gsum = 0.f;
    for (int l = 0; l < L_; ++l) {
      float g = gammas[tid*L_ + l];
      gsum += fminf(fmaxf(g, 0.f), 1.f);
    }
    gavg[tid] = gsum * (1.f / L_);
  }
  const int i = tid & 31, q = tid >> 5;
  float acc = 0.f;
  for (int s = q; s < 64; s += 4)
    acc += partial[((size_t)s*B_ + b)*I_ + i];
  cvred[q][i] = acc;
  __syncthreads();
  if (tid < I_) {
    float cv = cvred[0][i] + cvred[1][i] + cvred[2][i] + cvred[3][i];
    #pragma unroll
    for (int j = 0; j < J_; ++j) {
      const float* bw   = best + ((size_t)j*B_ + b)*L_;
      const float* wrow = body_w + (size_t)(j*I_ + i)*L_;
      float d = body_b[j*I_ + i];
      for (int c = 0; c < L_; ++c) d = fmaf(bw[c], wrow[c], d);
      cv += gavg[j] * d;
    }
    cvf[i] = cv;
  }
  __syncthreads();
  float oacc = head_b[tid];
  #pragma unroll
  for (int i2 = 0; i2 < I_; ++i2) oacc = fmaf(cvf[i2], head_w[tid*I_ + i2], oacc);
  out[(size_t)b*O_ + tid] = conf[b] * oacc;
}

extern "C" void kernel_launch(void* const* d_in, const int* in_sizes, int n_in,
                              void* d_out, int out_size, void* d_ws, size_t ws_size,
                              hipStream_t stream) {
  const float* wm        = (const float*)d_in[0];
  const float* constants = (const float*)d_in[1];
  const float* gammas    = (const float*)d_in[2];
  const float* body_w    = (const float*)d_in[3];
  const float* body_b    = (const float*)d_in[4];
  const float* slot_w    = (const float*)d_in[5];
  const float* slot_b    = (const float*)d_in[6];
  const float* head_w    = (const float*)d_in[7];
  const float* head_b    = (const float*)d_in[8];
  float* out = (float*)d_out;

  float* ws      = (float*)d_ws;
  float* wcg     = ws;                      // 512
  float* w1g     = wcg + J_*L_;             // 512
  float* Ag      = w1g + J_*L_;             // 16 (pad)
  float* best    = Ag + 16;                 // 262144
  float* conf    = best + (size_t)J_*B_*L_; // 512
  float* partial = conf + B_;               // 1048576

  hipLaunchKernelGGL(k0_prep, dim3(1), dim3(64), 0, stream,
                     constants, gammas, wcg, w1g, Ag);
  hipLaunchKernelGGL(k12_fused, dim3(B_), dim3(256), 0, stream,
                     wm, wcg, w1g, Ag, best, conf);
  hipLaunchKernelGGL(k3_slot, dim3(16, 64), dim3(256), 0, stream,
                     slot_w, slot_b, best, partial);
  hipLaunchKernelGGL(k4_head, dim3(B_), dim3(128), 0, stream,
                     partial, best, gammas, body_w, body_b, head_w, head_b, conf, out);
}

// Round 3
// 311.010 us; speedup vs baseline: 1.3656x; 1.1286x over previous
//
#include <hip/hip_runtime.h>
#include <cstdint>
#include <cstddef>

#define B_ 512
#define W_ 1024
#define L_ 64
#define J_ 8
#define I_ 32
#define O_ 128

// ws layout (floats):
// wcg   : [J][L]        = 512      @ 0
// w1g   : [J][L]        = 512
// Ag    : [J] (+pad)    = 16
// best  : [J][B][L]     = 262144
// conf  : [B]           = 512
// partial:[64][B][I]    = 1048576
// bpart : [2][J][B][L]  = 524288   (unnormalized per-half best)
// stats : [2][B][J][4]  = 32768    (m0, E, M=sum e*s, pad)

// ---------------------------------------------------------------- K0: tiny precompute of wc, w1, A
__global__ __launch_bounds__(64) void k0_prep(const float* __restrict__ constants,
    const float* __restrict__ gammas, float* __restrict__ wcg,
    float* __restrict__ w1g, float* __restrict__ Ag)
{
  const int l = threadIdx.x;
  #pragma unroll
  for (int j = 0; j < J_; ++j) {
    float g = gammas[j*L_ + l];
    g = fminf(fmaxf(g, 0.f), 1.f);
    float c = constants[j*L_ + l];
    float w1 = 1.f - g;
    w1g[j*L_ + l] = w1;
    wcg[j*L_ + l] = w1 * c;
  }
  if (l < J_) {
    float a = 0.f;
    for (int c = 0; c < L_; ++c) {
      float g = gammas[l*L_ + c];
      g = fminf(fmaxf(g, 0.f), 1.f);
      float cc = constants[l*L_ + c];
      a += (1.f - g) * cc * cc;
    }
    Ag[l] = a;
  }
}

// ---------------------------------------------------------------- K12: half-W flash pass (scores+exp+partial best)
__global__ __launch_bounds__(256, 4) void k12_fused(const float* __restrict__ wm,
    const float* __restrict__ wcg, const float* __restrict__ w1g,
    const float* __restrict__ Ag, float* __restrict__ bpart, float* __restrict__ stats)
{
  __shared__ __align__(16) float xs[128 * 68];   // 34816 B
  __shared__ __align__(16) float es[J_ * 128];   // 4096 B
  __shared__ float redA[4][4], redB[4][4];
  __shared__ float bcast[J_];

  const int tid = threadIdx.x;
  const int b = blockIdx.x, h = blockIdx.y;
  const int lane = tid & 63, wv = tid >> 6;
  const int w = tid & 127;                       // score-phase row
  const int jh = tid >> 7;                       // 0: j=0..3, 1: j=4..7
  const int jbase = __builtin_amdgcn_readfirstlane(jh << 2);
  const int lq = tid & 15, wsl = tid >> 4;       // best-phase mapping

  float accb[J_][4];
  #pragma unroll
  for (int j = 0; j < J_; ++j)
    #pragma unroll
    for (int q = 0; q < 4; ++q) accb[j][q] = 0.f;
  float esum[4], msum[4], m0[4];
  #pragma unroll
  for (int jj = 0; jj < 4; ++jj) { esum[jj] = 0.f; msum[jj] = 0.f; }

  const float* wmb = wm + (size_t)b * (W_*L_) + (size_t)h * (512*L_);

  for (int ch = 0; ch < 4; ++ch) {
    __syncthreads();   // xs about to be overwritten
    const float4* src = (const float4*)(wmb + ch * (128*L_));
    #pragma unroll
    for (int k = 0; k < 8; ++k) {
      int f = k*256 + tid;
      float4 v = src[f];
      int rw = f >> 4, lw = f & 15;
      *(float4*)&xs[rw*68 + lw*4] = v;
    }
    __syncthreads();

    // ---- score: thread owns (w, j = jbase..jbase+3)
    float a1[4], a2[4];
    #pragma unroll
    for (int jj = 0; jj < 4; ++jj) { a1[jj] = 0.f; a2[jj] = 0.f; }
    #pragma unroll
    for (int c = 0; c < 16; ++c) {
      float4 x = *(const float4*)&xs[w*68 + c*4];
      float4 xq;
      xq.x = x.x*x.x; xq.y = x.y*x.y; xq.z = x.z*x.z; xq.w = x.w*x.w;
      #pragma unroll
      for (int jj = 0; jj < 4; ++jj) {
        float4 wc4 = *(const float4*)(wcg + (jbase+jj)*L_ + c*4);   // uniform -> s_load
        float4 w14 = *(const float4*)(w1g + (jbase+jj)*L_ + c*4);
        a1[jj] = fmaf(wc4.x, x.x, a1[jj]);
        a1[jj] = fmaf(wc4.y, x.y, a1[jj]);
        a1[jj] = fmaf(wc4.z, x.z, a1[jj]);
        a1[jj] = fmaf(wc4.w, x.w, a1[jj]);
        a2[jj] = fmaf(w14.x, xq.x, a2[jj]);
        a2[jj] = fmaf(w14.y, xq.y, a2[jj]);
        a2[jj] = fmaf(w14.z, xq.z, a2[jj]);
        a2[jj] = fmaf(w14.w, xq.w, a2[jj]);
      }
    }
    float s[4];
    #pragma unroll
    for (int jj = 0; jj < 4; ++jj)
      s[jj] = Ag[jbase+jj] - 2.f*a1[jj] + a2[jj];

    // ---- per-half stabilizer from chunk 0 (scores >= 0)
    if (ch == 0) {
      #pragma unroll
      for (int jj = 0; jj < 4; ++jj) {
        float mn = s[jj];
        #pragma unroll
        for (int off = 1; off < 64; off <<= 1)
          mn = fminf(mn, __shfl_xor(mn, off));
        if (lane == 0) redA[wv][jj] = mn;
      }
      __syncthreads();
      if (tid < J_) {
        int jj = tid & 3;
        bcast[tid] = (tid < 4) ? fminf(redA[0][jj], redA[1][jj])
                               : fminf(redA[2][jj], redA[3][jj]);
      }
      __syncthreads();
      #pragma unroll
      for (int jj = 0; jj < 4; ++jj) m0[jj] = bcast[jbase+jj];
    }

    // ---- e + running sums + e to LDS
    #pragma unroll
    for (int jj = 0; jj < 4; ++jj) {
      float e = __expf(m0[jj] - s[jj]);
      esum[jj] += e;
      msum[jj] = fmaf(e, s[jj], msum[jj]);
      es[(jbase+jj)*128 + w] = e;
    }
    __syncthreads();

    // ---- accumulate partial best: thread owns lq, rows wsl*8..wsl*8+8
    #pragma unroll
    for (int tg = 0; tg < 2; ++tg) {
      float4 e4[J_];
      #pragma unroll
      for (int j = 0; j < J_; ++j)
        e4[j] = *(const float4*)&es[j*128 + wsl*8 + tg*4];
      #pragma unroll
      for (int t = 0; t < 4; ++t) {
        int w2 = wsl*8 + tg*4 + t;
        float4 x = *(const float4*)&xs[w2*68 + lq*4];
        #pragma unroll
        for (int j = 0; j < J_; ++j) {
          float ej = (t == 0) ? e4[j].x : (t == 1) ? e4[j].y
                   : (t == 2) ? e4[j].z : e4[j].w;
          accb[j][0] = fmaf(ej, x.x, accb[j][0]);
          accb[j][1] = fmaf(ej, x.y, accb[j][1]);
          accb[j][2] = fmaf(ej, x.z, accb[j][2]);
          accb[j][3] = fmaf(ej, x.w, accb[j][3]);
        }
      }
    }
  }

  // ---- block-reduce esum/msum; write stats
  #pragma unroll
  for (int jj = 0; jj < 4; ++jj) {
    float e = esum[jj], m = msum[jj];
    #pragma unroll
    for (int off = 1; off < 64; off <<= 1) {
      e += __shfl_xor(e, off);
      m += __shfl_xor(m, off);
    }
    if (lane == 0) { redA[wv][jj] = e; redB[wv][jj] = m; }
  }
  __syncthreads();
  if (tid < J_) {
    int jj = tid & 3;
    float E = (tid < 4) ? redA[0][jj] + redA[1][jj] : redA[2][jj] + redA[3][jj];
    float M = (tid < 4) ? redB[0][jj] + redB[1][jj] : redB[2][jj] + redB[3][jj];
    float* st = stats + (((size_t)h*B_ + b)*J_ + tid)*4;
    st[0] = bcast[tid]; st[1] = E; st[2] = M;
  }

  // ---- reduce accb over 16 w-slots (reuse xs; sync above guarantees reads done)
  #pragma unroll
  for (int j = 0; j < J_; ++j)
    *(float4*)&xs[((wsl*J_ + j)*16 + lq)*4] = *(float4*)accb[j];
  __syncthreads();
  if (tid < J_*16) {
    int j = tid >> 4, q = tid & 15;
    float4 sum = make_float4(0.f, 0.f, 0.f, 0.f);
    #pragma unroll
    for (int s2 = 0; s2 < 16; ++s2) {
      float4 p = *(const float4*)&xs[((s2*J_ + j)*16 + q)*4];
      sum.x += p.x; sum.y += p.y; sum.z += p.z; sum.w += p.w;
    }
    *(float4*)&bpart[(((size_t)h*J_ + j)*B_ + b)*L_ + q*4] = sum;
  }
}

// ---------------------------------------------------------------- K2b: combine the two W-halves
__global__ __launch_bounds__(128) void k2b_combine(const float* __restrict__ bpart,
    const float* __restrict__ stats, float* __restrict__ best, float* __restrict__ conf)
{
  __shared__ float mred[J_];
  const int b = blockIdx.x, tid = threadIdx.x;
  const int j = tid >> 4, q = tid & 15;
  const float* st0 = stats + ((size_t)b*J_ + j)*4;
  const float* st1 = stats + (((size_t)B_ + b)*J_ + j)*4;
  float m0a = st0[0], E0 = st0[1], M0 = st0[2];
  float m0b = st1[0], E1 = st1[1], M1 = st1[2];
  float M = fminf(m0a, m0b);
  float s0 = __expf(M - m0a), s1 = __expf(M - m0b);
  float E = s0*E0 + s1*E1;
  float inv = 1.f / E;
  float4 p0 = *(const float4*)&bpart[((size_t)j*B_ + b)*L_ + q*4];
  float4 p1 = *(const float4*)&bpart[(((size_t)J_ + j)*B_ + b)*L_ + q*4];
  float4 o;
  o.x = (s0*p0.x + s1*p1.x) * inv;
  o.y = (s0*p0.y + s1*p1.y) * inv;
  o.z = (s0*p0.z + s1*p1.z) * inv;
  o.w = (s0*p0.w + s1*p1.w) * inv;
  *(float4*)&best[((size_t)j*B_ + b)*L_ + q*4] = o;
  if (q == 0) mred[j] = (s0*M0 + s1*M1) * inv;
  __syncthreads();
  if (tid == 0) {
    float mq = 0.f;
    #pragma unroll
    for (int jj = 0; jj < J_; ++jj) mq += mred[jj];
    conf[b] = __expf(-mq);
  }
}

// ---------------------------------------------------------------- K3: slot logits + softmax-over-i (2-b ILP)
__global__ __launch_bounds__(256) void k3_slot(const float* __restrict__ slot_w,
    const float* __restrict__ slot_b, const float* __restrict__ best,
    float* __restrict__ partial)
{
  const int bx = blockIdx.y;            // (j, lgroup) slow dim
  const int j = bx >> 3, lg = bx & 7;
  const int bc = blockIdx.x;            // b-chunk fast dim -> L2 reuse
  const int tid = threadIdx.x;
  const int wv = tid >> 6, lane = tid & 63;
  const int l2 = lane >> 5, i = lane & 31;
  const int l = lg*8 + wv*2 + l2;
  const int r = l*I_ + i;

  const float* swr = slot_w + ((size_t)j*(L_*I_) + r) * L_;
  float sw[L_];
  #pragma unroll
  for (int c = 0; c < 16; ++c) {
    float4 t = ((const float4*)swr)[c];
    sw[c*4+0] = t.x; sw[c*4+1] = t.y; sw[c*4+2] = t.z; sw[c*4+3] = t.w;
  }
  const float sb = slot_b[j*(L_*I_) + r];
  const float* bestj = best + (size_t)j * B_ * L_;
  float* pout = partial + (size_t)bx * (B_*I_);
  const int lidx = lg*8 + wv*2;

  for (int bi = 0; bi < 32; bi += 2) {
    const int b0 = bc*32 + bi;
    const float* bw0 = bestj + (size_t)b0 * L_;   // block-uniform -> s_load
    const float* bw1 = bw0 + L_;
    float p00 = sb, p01 = 0.f, p02 = 0.f, p03 = 0.f;
    float p10 = sb, p11 = 0.f, p12 = 0.f, p13 = 0.f;
    #pragma unroll
    for (int c = 0; c < L_; c += 4) {
      p00 = fmaf(bw0[c+0], sw[c+0], p00);
      p10 = fmaf(bw1[c+0], sw[c+0], p10);
      p01 = fmaf(bw0[c+1], sw[c+1], p01);
      p11 = fmaf(bw1[c+1], sw[c+1], p11);
      p02 = fmaf(bw0[c+2], sw[c+2], p02);
      p12 = fmaf(bw1[c+2], sw[c+2], p12);
      p03 = fmaf(bw0[c+3], sw[c+3], p03);
      p13 = fmaf(bw1[c+3], sw[c+3], p13);
    }
    float lg0 = (p00 + p01) + (p02 + p03);
    float lg1 = (p10 + p11) + (p12 + p13);
    float m0v = lg0, m1v = lg1;
    #pragma unroll
    for (int mask = 16; mask; mask >>= 1) {
      m0v = fmaxf(m0v, __shfl_xor(m0v, mask));
      m1v = fmaxf(m1v, __shfl_xor(m1v, mask));
    }
    float e0 = __expf(lg0 - m0v), e1 = __expf(lg1 - m1v);
    float s0 = e0, s1 = e1;
    #pragma unroll
    for (int mask = 16; mask; mask >>= 1) {
      s0 += __shfl_xor(s0, mask);
      s1 += __shfl_xor(s1, mask);
    }
    float bv0 = l2 ? bw0[lidx+1] : bw0[lidx];
    float bv1 = l2 ? bw1[lidx+1] : bw1[lidx];
    float c0 = (e0 / s0) * bv0;
    float c1 = (e1 / s1) * bv1;
    c0 += __shfl_xor(c0, 32);
    c1 += __shfl_xor(c1, 32);
    if (l2 == 0) {
      pout[(size_t)b0*I_ + i] = c0;
      pout[(size_t)(b0+1)*I_ + i] = c1;
    }
  }
}

// ---------------------------------------------------------------- K4: reduce partials + body + head + confidence
__global__ __launch_bounds__(128) void k4_head(const float* __restrict__ partial,
    const float* __restrict__ best, const float* __restrict__ gammas,
    const float* __restrict__ body_w, const float* __restrict__ body_b,
    const float* __restrict__ head_w, const float* __restrict__ head_b,
    const float* __restrict__ conf, float* __restrict__ out)
{
  __shared__ float gavg[J_];
  __shared__ float cvred[4][I_];
  __shared__ float cvf[I_];
  const int b = blockIdx.x, tid = threadIdx.x;
  if (tid < J_) {
    float gsum = 0.f;
    for (int l = 0; l < L_; ++l) {
      float g = gammas[tid*L_ + l];
      gsum += fminf(fmaxf(g, 0.f), 1.f);
    }
    gavg[tid] = gsum * (1.f / L_);
  }
  const int i = tid & 31, q = tid >> 5;
  float acc = 0.f;
  for (int s = q; s < 64; s += 4)
    acc += partial[((size_t)s*B_ + b)*I_ + i];
  cvred[q][i] = acc;
  __syncthreads();
  if (tid < I_) {
    float cv = cvred[0][i] + cvred[1][i] + cvred[2][i] + cvred[3][i];
    #pragma unroll
    for (int j = 0; j < J_; ++j) {
      const float* bw   = best + ((size_t)j*B_ + b)*L_;
      const float* wrow = body_w + (size_t)(j*I_ + i)*L_;
      float d = body_b[j*I_ + i];
      for (int c = 0; c < L_; ++c) d = fmaf(bw[c], wrow[c], d);
      cv += gavg[j] * d;
    }
    cvf[i] = cv;
  }
  __syncthreads();
  float oacc = head_b[tid];
  #pragma unroll
  for (int i2 = 0; i2 < I_; ++i2) oacc = fmaf(cvf[i2], head_w[tid*I_ + i2], oacc);
  out[(size_t)b*O_ + tid] = conf[b] * oacc;
}

extern "C" void kernel_launch(void* const* d_in, const int* in_sizes, int n_in,
                              void* d_out, int out_size, void* d_ws, size_t ws_size,
                              hipStream_t stream) {
  const float* wm        = (const float*)d_in[0];
  const float* constants = (const float*)d_in[1];
  const float* gammas    = (const float*)d_in[2];
  const float* body_w    = (const float*)d_in[3];
  const float* body_b    = (const float*)d_in[4];
  const float* slot_w    = (const float*)d_in[5];
  const float* slot_b    = (const float*)d_in[6];
  const float* head_w    = (const float*)d_in[7];
  const float* head_b    = (const float*)d_in[8];
  float* out = (float*)d_out;

  float* ws      = (float*)d_ws;
  float* wcg     = ws;                          // 512
  float* w1g     = wcg + J_*L_;                 // 512
  float* Ag      = w1g + J_*L_;                 // 16
  float* best    = Ag + 16;                     // 262144
  float* conf    = best + (size_t)J_*B_*L_;     // 512
  float* partial = conf + B_;                   // 1048576
  float* bpart   = partial + (size_t)64*B_*I_;  // 524288
  float* stats   = bpart + (size_t)2*J_*B_*L_;  // 32768

  hipLaunchKernelGGL(k0_prep, dim3(1), dim3(64), 0, stream,
                     constants, gammas, wcg, w1g, Ag);
  hipLaunchKernelGGL(k12_fused, dim3(B_, 2), dim3(256), 0, stream,
                     wm, wcg, w1g, Ag, bpart, stats);
  hipLaunchKernelGGL(k2b_combine, dim3(B_), dim3(128), 0, stream,
                     bpart, stats, best, conf);
  hipLaunchKernelGGL(k3_slot, dim3(16, 64), dim3(256), 0, stream,
                     slot_w, slot_b, best, partial);
  hipLaunchKernelGGL(k4_head, dim3(B_), dim3(128), 0, stream,
                     partial, best, gammas, body_w, body_b, head_w, head_b, conf, out);
}

// Round 4
// 289.120 us; speedup vs baseline: 1.4690x; 1.0757x over previous
//
#include <hip/hip_runtime.h>
#include <cstdint>
#include <cstddef>

#define B_ 512
#define W_ 1024
#define L_ 64
#define J_ 8
#define I_ 32
#define O_ 128

// ws layout (floats):
// wcg   : [J][L]        = 512
// w1g   : [J][L]        = 512
// Ag    : [J] (+pad)    = 16
// best  : [J][B][L]     = 262144
// conf  : [B]           = 512
// partial:[64][B][I]    = 1048576
// bpart : [2][J][B][L]  = 524288
// stats : [2][B][J][4]  = 32768

// ---------------------------------------------------------------- K0
__global__ __launch_bounds__(64) void k0_prep(const float* __restrict__ constants,
    const float* __restrict__ gammas, float* __restrict__ wcg,
    float* __restrict__ w1g, float* __restrict__ Ag)
{
  const int l = threadIdx.x;
  #pragma unroll
  for (int j = 0; j < J_; ++j) {
    float g = gammas[j*L_ + l];
    g = fminf(fmaxf(g, 0.f), 1.f);
    float c = constants[j*L_ + l];
    float w1 = 1.f - g;
    w1g[j*L_ + l] = w1;
    wcg[j*L_ + l] = w1 * c;
  }
  if (l < J_) {
    float a = 0.f;
    for (int c = 0; c < L_; ++c) {
      float g = gammas[l*L_ + c];
      g = fminf(fmaxf(g, 0.f), 1.f);
      float cc = constants[l*L_ + c];
      a += (1.f - g) * cc * cc;
    }
    Ag[l] = a;
  }
}

// ---------------------------------------------------------------- K12: half-W flash pass
// launch_bounds(256,2): R3's (256,4) forced VGPR=64 + scratch spills
// (WRITE_SIZE 72 MB vs 2 MB actual). (256,2) compiles to 128 VGPR, no
// spill; 128 regs + 39424 B LDS still allows 4 blocks/CU.
__global__ __launch_bounds__(256, 2) void k12_fused(const float* __restrict__ wm,
    const float* __restrict__ wcg, const float* __restrict__ w1g,
    const float* __restrict__ Ag, float* __restrict__ bpart, float* __restrict__ stats)
{
  __shared__ __align__(16) float xs[128 * 68];   // 34816 B
  __shared__ __align__(16) float es[J_ * 128];   // 4096 B
  __shared__ float redA[4][4], redB[4][4];
  __shared__ float bcast[J_];

  const int tid = threadIdx.x;
  const int b = blockIdx.x, h = blockIdx.y;
  const int lane = tid & 63, wv = tid >> 6;
  const int w = tid & 127;
  const int jh = tid >> 7;
  const int jbase = __builtin_amdgcn_readfirstlane(jh << 2);
  const int lq = tid & 15, wsl = tid >> 4;

  float accb[J_][4];
  #pragma unroll
  for (int j = 0; j < J_; ++j)
    #pragma unroll
    for (int q = 0; q < 4; ++q) accb[j][q] = 0.f;
  float esum[4], msum[4], m0[4];
  #pragma unroll
  for (int jj = 0; jj < 4; ++jj) { esum[jj] = 0.f; msum[jj] = 0.f; }

  const float* wmb = wm + (size_t)b * (W_*L_) + (size_t)h * (512*L_);

  for (int ch = 0; ch < 4; ++ch) {
    __syncthreads();
    const float4* src = (const float4*)(wmb + ch * (128*L_));
    #pragma unroll
    for (int k = 0; k < 8; ++k) {
      int f = k*256 + tid;
      float4 v = src[f];
      int rw = f >> 4, lw = f & 15;
      *(float4*)&xs[rw*68 + lw*4] = v;
    }
    __syncthreads();

    // ---- score: thread owns (w, j = jbase..jbase+3)
    float a1[4], a2[4];
    #pragma unroll
    for (int jj = 0; jj < 4; ++jj) { a1[jj] = 0.f; a2[jj] = 0.f; }
    #pragma unroll
    for (int c = 0; c < 16; ++c) {
      float4 x = *(const float4*)&xs[w*68 + c*4];
      float4 xq;
      xq.x = x.x*x.x; xq.y = x.y*x.y; xq.z = x.z*x.z; xq.w = x.w*x.w;
      #pragma unroll
      for (int jj = 0; jj < 4; ++jj) {
        float4 wc4 = *(const float4*)(wcg + (jbase+jj)*L_ + c*4);   // uniform -> s_load
        float4 w14 = *(const float4*)(w1g + (jbase+jj)*L_ + c*4);
        a1[jj] = fmaf(wc4.x, x.x, a1[jj]);
        a1[jj] = fmaf(wc4.y, x.y, a1[jj]);
        a1[jj] = fmaf(wc4.z, x.z, a1[jj]);
        a1[jj] = fmaf(wc4.w, x.w, a1[jj]);
        a2[jj] = fmaf(w14.x, xq.x, a2[jj]);
        a2[jj] = fmaf(w14.y, xq.y, a2[jj]);
        a2[jj] = fmaf(w14.z, xq.z, a2[jj]);
        a2[jj] = fmaf(w14.w, xq.w, a2[jj]);
      }
    }
    float s[4];
    #pragma unroll
    for (int jj = 0; jj < 4; ++jj)
      s[jj] = Ag[jbase+jj] - 2.f*a1[jj] + a2[jj];

    if (ch == 0) {
      #pragma unroll
      for (int jj = 0; jj < 4; ++jj) {
        float mn = s[jj];
        #pragma unroll
        for (int off = 1; off < 64; off <<= 1)
          mn = fminf(mn, __shfl_xor(mn, off));
        if (lane == 0) redA[wv][jj] = mn;
      }
      __syncthreads();
      if (tid < J_) {
        int jj = tid & 3;
        bcast[tid] = (tid < 4) ? fminf(redA[0][jj], redA[1][jj])
                               : fminf(redA[2][jj], redA[3][jj]);
      }
      __syncthreads();
      #pragma unroll
      for (int jj = 0; jj < 4; ++jj) m0[jj] = bcast[jbase+jj];
    }

    #pragma unroll
    for (int jj = 0; jj < 4; ++jj) {
      float e = __expf(m0[jj] - s[jj]);
      esum[jj] += e;
      msum[jj] = fmaf(e, s[jj], msum[jj]);
      es[(jbase+jj)*128 + w] = e;
    }
    __syncthreads();

    // ---- accumulate partial best: stage x[4] once, then per-j e-loads
    // (lower transient register pressure than e4[8]-first ordering)
    #pragma unroll
    for (int tg = 0; tg < 2; ++tg) {
      float4 x[4];
      #pragma unroll
      for (int t = 0; t < 4; ++t)
        x[t] = *(const float4*)&xs[(wsl*8 + tg*4 + t)*68 + lq*4];
      #pragma unroll
      for (int j = 0; j < J_; ++j) {
        float4 e4 = *(const float4*)&es[j*128 + wsl*8 + tg*4];
        accb[j][0] = fmaf(e4.x, x[0].x, accb[j][0]);
        accb[j][1] = fmaf(e4.x, x[0].y, accb[j][1]);
        accb[j][2] = fmaf(e4.x, x[0].z, accb[j][2]);
        accb[j][3] = fmaf(e4.x, x[0].w, accb[j][3]);
        accb[j][0] = fmaf(e4.y, x[1].x, accb[j][0]);
        accb[j][1] = fmaf(e4.y, x[1].y, accb[j][1]);
        accb[j][2] = fmaf(e4.y, x[1].z, accb[j][2]);
        accb[j][3] = fmaf(e4.y, x[1].w, accb[j][3]);
        accb[j][0] = fmaf(e4.z, x[2].x, accb[j][0]);
        accb[j][1] = fmaf(e4.z, x[2].y, accb[j][1]);
        accb[j][2] = fmaf(e4.z, x[2].z, accb[j][2]);
        accb[j][3] = fmaf(e4.z, x[2].w, accb[j][3]);
        accb[j][0] = fmaf(e4.w, x[3].x, accb[j][0]);
        accb[j][1] = fmaf(e4.w, x[3].y, accb[j][1]);
        accb[j][2] = fmaf(e4.w, x[3].z, accb[j][2]);
        accb[j][3] = fmaf(e4.w, x[3].w, accb[j][3]);
      }
    }
  }

  // ---- block-reduce esum/msum; write stats
  #pragma unroll
  for (int jj = 0; jj < 4; ++jj) {
    float e = esum[jj], m = msum[jj];
    #pragma unroll
    for (int off = 1; off < 64; off <<= 1) {
      e += __shfl_xor(e, off);
      m += __shfl_xor(m, off);
    }
    if (lane == 0) { redA[wv][jj] = e; redB[wv][jj] = m; }
  }
  __syncthreads();
  if (tid < J_) {
    int jj = tid & 3;
    float E = (tid < 4) ? redA[0][jj] + redA[1][jj] : redA[2][jj] + redA[3][jj];
    float M = (tid < 4) ? redB[0][jj] + redB[1][jj] : redB[2][jj] + redB[3][jj];
    float* st = stats + (((size_t)h*B_ + b)*J_ + tid)*4;
    st[0] = bcast[tid]; st[1] = E; st[2] = M;
  }

  // ---- reduce accb over 16 w-slots (reuse xs)
  #pragma unroll
  for (int j = 0; j < J_; ++j)
    *(float4*)&xs[((wsl*J_ + j)*16 + lq)*4] = *(float4*)accb[j];
  __syncthreads();
  if (tid < J_*16) {
    int j = tid >> 4, q = tid & 15;
    float4 sum = make_float4(0.f, 0.f, 0.f, 0.f);
    #pragma unroll
    for (int s2 = 0; s2 < 16; ++s2) {
      float4 p = *(const float4*)&xs[((s2*J_ + j)*16 + q)*4];
      sum.x += p.x; sum.y += p.y; sum.z += p.z; sum.w += p.w;
    }
    *(float4*)&bpart[(((size_t)h*J_ + j)*B_ + b)*L_ + q*4] = sum;
  }
}

// ---------------------------------------------------------------- K2b: combine halves
__global__ __launch_bounds__(128) void k2b_combine(const float* __restrict__ bpart,
    const float* __restrict__ stats, float* __restrict__ best, float* __restrict__ conf)
{
  __shared__ float mred[J_];
  const int b = blockIdx.x, tid = threadIdx.x;
  const int j = tid >> 4, q = tid & 15;
  const float* st0 = stats + ((size_t)b*J_ + j)*4;
  const float* st1 = stats + (((size_t)B_ + b)*J_ + j)*4;
  float m0a = st0[0], E0 = st0[1], M0 = st0[2];
  float m0b = st1[0], E1 = st1[1], M1 = st1[2];
  float M = fminf(m0a, m0b);
  float s0 = __expf(M - m0a), s1 = __expf(M - m0b);
  float E = s0*E0 + s1*E1;
  float inv = 1.f / E;
  float4 p0 = *(const float4*)&bpart[((size_t)j*B_ + b)*L_ + q*4];
  float4 p1 = *(const float4*)&bpart[(((size_t)J_ + j)*B_ + b)*L_ + q*4];
  float4 o;
  o.x = (s0*p0.x + s1*p1.x) * inv;
  o.y = (s0*p0.y + s1*p1.y) * inv;
  o.z = (s0*p0.z + s1*p1.z) * inv;
  o.w = (s0*p0.w + s1*p1.w) * inv;
  *(float4*)&best[((size_t)j*B_ + b)*L_ + q*4] = o;
  if (q == 0) mred[j] = (s0*M0 + s1*M1) * inv;
  __syncthreads();
  if (tid == 0) {
    float mq = 0.f;
    #pragma unroll
    for (int jj = 0; jj < J_; ++jj) mq += mred[jj];
    conf[b] = __expf(-mq);
  }
}

// ---------------------------------------------------------------- K3: slot path, 4-way b ILP
__global__ __launch_bounds__(256) void k3_slot(const float* __restrict__ slot_w,
    const float* __restrict__ slot_b, const float* __restrict__ best,
    float* __restrict__ partial)
{
  const int bx = blockIdx.y;            // (j, lgroup)
  const int j = bx >> 3, lg = bx & 7;
  const int bc = blockIdx.x;            // b-chunk fast dim
  const int tid = threadIdx.x;
  const int wv = tid >> 6, lane = tid & 63;
  const int l2 = lane >> 5, i = lane & 31;
  const int l = lg*8 + wv*2 + l2;
  const int r = l*I_ + i;

  const float* swr = slot_w + ((size_t)j*(L_*I_) + r) * L_;
  float sw[L_];
  #pragma unroll
  for (int c = 0; c < 16; ++c) {
    float4 t = ((const float4*)swr)[c];
    sw[c*4+0] = t.x; sw[c*4+1] = t.y; sw[c*4+2] = t.z; sw[c*4+3] = t.w;
  }
  const float sb = slot_b[j*(L_*I_) + r];
  const float* bestj = best + (size_t)j * B_ * L_;
  float* pout = partial + (size_t)bx * (B_*I_);
  const int lidx = lg*8 + wv*2;

  for (int bi = 0; bi < 32; bi += 4) {
    const int b0 = bc*32 + bi;
    const float* bw[4];
    #pragma unroll
    for (int u = 0; u < 4; ++u) bw[u] = bestj + (size_t)(b0+u) * L_;  // uniform -> s_load
    float pa[4], pb[4];
    #pragma unroll
    for (int u = 0; u < 4; ++u) { pa[u] = sb; pb[u] = 0.f; }
    #pragma unroll
    for (int c = 0; c < L_; c += 2) {
      #pragma unroll
      for (int u = 0; u < 4; ++u) {
        pa[u] = fmaf(bw[u][c+0], sw[c+0], pa[u]);
        pb[u] = fmaf(bw[u][c+1], sw[c+1], pb[u]);
      }
    }
    float lgt[4], mx[4], e[4], sm[4];
    #pragma unroll
    for (int u = 0; u < 4; ++u) { lgt[u] = pa[u] + pb[u]; mx[u] = lgt[u]; }
    #pragma unroll
    for (int mask = 16; mask; mask >>= 1)
      #pragma unroll
      for (int u = 0; u < 4; ++u) mx[u] = fmaxf(mx[u], __shfl_xor(mx[u], mask));
    #pragma unroll
    for (int u = 0; u < 4; ++u) { e[u] = __expf(lgt[u] - mx[u]); sm[u] = e[u]; }
    #pragma unroll
    for (int mask = 16; mask; mask >>= 1)
      #pragma unroll
      for (int u = 0; u < 4; ++u) sm[u] += __shfl_xor(sm[u], mask);
    float cv[4];
    #pragma unroll
    for (int u = 0; u < 4; ++u) {
      float bv = l2 ? bw[u][lidx+1] : bw[u][lidx];
      cv[u] = (e[u] / sm[u]) * bv;
    }
    #pragma unroll
    for (int u = 0; u < 4; ++u) cv[u] += __shfl_xor(cv[u], 32);
    if (l2 == 0) {
      #pragma unroll
      for (int u = 0; u < 4; ++u)
        pout[(size_t)(b0+u)*I_ + i] = cv[u];
    }
  }
}

// ---------------------------------------------------------------- K4: reduce + body + head + confidence
__global__ __launch_bounds__(128) void k4_head(const float* __restrict__ partial,
    const float* __restrict__ best, const float* __restrict__ gammas,
    const float* __restrict__ body_w, const float* __restrict__ body_b,
    const float* __restrict__ head_w, const float* __restrict__ head_b,
    const float* __restrict__ conf, float* __restrict__ out)
{
  __shared__ float gavg[J_];
  __shared__ float cvred[4][I_];
  __shared__ float cvf[I_];
  const int b = blockIdx.x, tid = threadIdx.x;
  const int i = tid & 31, q = tid >> 5;   // q in 0..3
  if (tid < J_) {
    float gsum = 0.f;
    for (int l = 0; l < L_; ++l) {
      float g = gammas[tid*L_ + l];
      gsum += fminf(fmaxf(g, 0.f), 1.f);
    }
    gavg[tid] = gsum * (1.f / L_);
  }
  __syncthreads();

  // slot partial reduce: 16 slices per thread
  float acc = 0.f;
  for (int s = q; s < 64; s += 4)
    acc += partial[((size_t)s*B_ + b)*I_ + i];

  // body: thread (q,i) handles j = q and j = q+4 (fully parallel over 128 thr)
  #pragma unroll
  for (int u = 0; u < 2; ++u) {
    const int j = q + u*4;
    const float* bwv  = best + ((size_t)j*B_ + b)*L_;
    const float* wrow = body_w + (size_t)(j*I_ + i)*L_;
    float d0 = body_b[j*I_ + i], d1 = 0.f, d2 = 0.f, d3 = 0.f;
    #pragma unroll
    for (int c = 0; c < L_; c += 4) {
      d0 = fmaf(bwv[c+0], wrow[c+0], d0);
      d1 = fmaf(bwv[c+1], wrow[c+1], d1);
      d2 = fmaf(bwv[c+2], wrow[c+2], d2);
      d3 = fmaf(bwv[c+3], wrow[c+3], d3);
    }
    acc = fmaf(gavg[j], (d0 + d1) + (d2 + d3), acc);
  }
  cvred[q][i] = acc;
  __syncthreads();
  if (tid < I_)
    cvf[i] = cvred[0][i] + cvred[1][i] + cvred[2][i] + cvred[3][i];
  __syncthreads();
  float oacc = head_b[tid];
  #pragma unroll
  for (int i2 = 0; i2 < I_; ++i2) oacc = fmaf(cvf[i2], head_w[tid*I_ + i2], oacc);
  out[(size_t)b*O_ + tid] = conf[b] * oacc;
}

extern "C" void kernel_launch(void* const* d_in, const int* in_sizes, int n_in,
                              void* d_out, int out_size, void* d_ws, size_t ws_size,
                              hipStream_t stream) {
  const float* wm        = (const float*)d_in[0];
  const float* constants = (const float*)d_in[1];
  const float* gammas    = (const float*)d_in[2];
  const float* body_w    = (const float*)d_in[3];
  const float* body_b    = (const float*)d_in[4];
  const float* slot_w    = (const float*)d_in[5];
  const float* slot_b    = (const float*)d_in[6];
  const float* head_w    = (const float*)d_in[7];
  const float* head_b    = (const float*)d_in[8];
  float* out = (float*)d_out;

  float* ws      = (float*)d_ws;
  float* wcg     = ws;
  float* w1g     = wcg + J_*L_;
  float* Ag      = w1g + J_*L_;
  float* best    = Ag + 16;
  float* conf    = best + (size_t)J_*B_*L_;
  float* partial = conf + B_;
  float* bpart   = partial + (size_t)64*B_*I_;
  float* stats   = bpart + (size_t)2*J_*B_*L_;

  hipLaunchKernelGGL(k0_prep, dim3(1), dim3(64), 0, stream,
                     constants, gammas, wcg, w1g, Ag);
  hipLaunchKernelGGL(k12_fused, dim3(B_, 2), dim3(256), 0, stream,
                     wm, wcg, w1g, Ag, bpart, stats);
  hipLaunchKernelGGL(k2b_combine, dim3(B_), dim3(128), 0, stream,
                     bpart, stats, best, conf);
  hipLaunchKernelGGL(k3_slot, dim3(16, 64), dim3(256), 0, stream,
                     slot_w, slot_b, best, partial);
  hipLaunchKernelGGL(k4_head, dim3(B_), dim3(128), 0, stream,
                     partial, best, gammas, body_w, body_b, head_w, head_b, conf, out);
}